// Round 7
// baseline (325.359 us; speedup 1.0000x reference)
//
#include <hip/hip_runtime.h>

#define B_    128
#define P_    16
#define NP_   256
#define EP_   1280
#define EPG_  2048
#define ODIM_ 256
#define NH_   128

typedef __attribute__((ext_vector_type(8))) short s8_t;
typedef __attribute__((ext_vector_type(4))) short s4_t;
typedef __attribute__((ext_vector_type(4))) float f4_t;

__device__ __forceinline__ unsigned short f2b(float x) {
  unsigned u = __builtin_bit_cast(unsigned, x);
  u = (u + 0x7fffu + ((u >> 16) & 1u)) >> 16;
  return (unsigned short)u;
}
__device__ __forceinline__ float b2f(short x) {
  unsigned u = ((unsigned)(unsigned short)x) << 16;
  return __builtin_bit_cast(float, u);
}

// ---------------------------------------------------------------------------
// Stage A: one block (256 thr) per plane graph (2048).
// R10: R9 + sched_barrier(0) fences at accumulator-group boundaries.
// R9's AGPR-halving was implemented but not honored: compiler interleaved
// group-0 pack with group-1 frag-build -> both acc groups live -> agpr=64,
// arch clamped to 64, ~8 regs spilled (WRITE 17MB, VGPR_Count=64).
// sched_barrier(0) forces group death -> regalloc reuses 32 AGPRs ->
// arch budget 96 >= ~72 demand -> spill-free 4 blocks/CU.
// Falsifier: if VGPR stays 64 / WRITE stays 17MB, partition is heuristic-fixed.
// ---------------------------------------------------------------------------
struct SmemA {
  float f[256];                                   // whole kernel (recon at end)
  union {
    __align__(16) unsigned short wT1[64 * 136];   // P1-P3: (W2|res2)^T staging
    __align__(16) unsigned short z2[256 * 40];    // P3-P7: z / h matrix
  } u1;
  __align__(16) unsigned short dW1T[128 * 36];    // P4-P7: dW1^T, stride 36
  union {
    struct { float S0a[256]; float S1a[256]; } a; // P1-P3
    float redf[512];                              // P6-P7
  } u2;
  float el2[256], er2[256];                       // P1 then P4-P5
  union {
    struct { float abg0[128], abg1[128], abg2[128]; } a;  // P2-P3
    struct { float al2v[32], ar2v[32], dW2v[128]; } b;    // P4-P7
  } u3;
  union {
    int cnt[256];                                 // P0
    struct { float scA[32], shA[32], dscA[64], dshA[64]; } b; // P6-P7
  } u4;
  unsigned short esrc[1280];                      // P0-P5
  int wtot[4];
  float r8[4][8]; float stat[8]; float wA[2], wB[2];
  float rlacc;
};

__global__ __launch_bounds__(256, 4) void plane_enc(
    const float* __restrict__ feat, const int* __restrict__ esrcg, const int* __restrict__ edstg,
    const float* __restrict__ W1, const float* __restrict__ al1, const float* __restrict__ ar1,
    const float* __restrict__ res1, const float* __restrict__ b1, const float* __restrict__ g1,
    const float* __restrict__ be1,
    const float* __restrict__ W2, const float* __restrict__ al2, const float* __restrict__ ar2,
    const float* __restrict__ res2, const float* __restrict__ g2, const float* __restrict__ be2,
    const float* __restrict__ dW1, const float* __restrict__ dg, const float* __restrict__ dbe,
    const float* __restrict__ dW2, const float* __restrict__ db2,
    float* __restrict__ rep_out, float* __restrict__ rlp_out)
{
  __shared__ SmemA s;
  const int g = blockIdx.x;
  const int p = g & 15;
  const int t = threadIdx.x;
  const int lane = t & 63, wv = t >> 6;
  const int l15 = lane & 15, quad = lane >> 4;

  s.f[t] = feat[g * NP_ + t];
  if (t == 0) s.rlacc = 0.f;
  s.u4.cnt[t] = 0;
  __syncthreads();

  const int* gs = esrcg + g * EP_;
  const int* gd = edstg + g * EP_;
  for (int k = t; k < EP_; k += 256) atomicAdd(&s.u4.cnt[gd[k]], 1);
  __syncthreads();
  int v = s.u4.cnt[t];
  int incl = v;
  #pragma unroll
  for (int off = 1; off < 64; off <<= 1) {
    int n = __shfl_up(incl, off, 64);
    if (lane >= off) incl += n;
  }
  if (lane == 63) s.wtot[wv] = incl;
  __syncthreads();
  int woff = 0;
  for (int w = 0; w < wv; w++) woff += s.wtot[w];
  const int myStart = woff + incl - v;
  const int myDeg = v;
  __syncthreads();
  s.u4.cnt[t] = myStart;
  __syncthreads();
  for (int k = t; k < EP_; k += 256) {
    int d = gd[k];
    int pos = atomicAdd(&s.u4.cnt[d], 1);
    s.esrc[pos] = (unsigned short)gs[k];
  }
  {
    const float* W2g = W2 + p * 4096;
    const float* Rg  = res2 + p * 4096;
    for (int q = 0; q < 16; q++) {
      int idx = t + 256 * q;
      int k = idx >> 5, n = idx & 31;
      s.u1.wT1[n * 136 + k]        = f2b(W2g[idx]);
      s.u1.wT1[(n + 32) * 136 + k] = f2b(Rg[idx]);
    }
  }
  if (t < 128) {
    float w1v = W1[p * 128 + t];
    s.el2[t] = w1v * al1[p * 128 + t];
    s.er2[t] = w1v * ar1[p * 128 + t];
  }
  __syncthreads();
  if (t < 2) {
    float a = 0.f, bq = 0.f;
    for (int d2 = 0; d2 < 64; d2++) { a += s.el2[t * 64 + d2]; bq += s.er2[t * 64 + d2]; }
    s.wA[t] = a; s.wB[t] = bq;
  }
  __syncthreads();

  const float fi = s.f[t];
  float S0, S1;
  {
    const float wa0 = s.wA[0], wb0 = s.wB[0], wa1 = s.wA[1], wb1 = s.wB[1];
    float m0 = -1e30f, m1 = -1e30f;
    for (int j = 0; j < myDeg; j++) {
      float fs = s.f[s.esrc[myStart + j]];
      float e0 = wa0 * fs + wb0 * fi; e0 = e0 > 0.f ? e0 : 0.2f * e0;
      float e1 = wa1 * fs + wb1 * fi; e1 = e1 > 0.f ? e1 : 0.2f * e1;
      m0 = fmaxf(m0, e0); m1 = fmaxf(m1, e1);
    }
    float ss0 = 0.f, ss1 = 0.f, U0 = 0.f, U1 = 0.f;
    for (int j = 0; j < myDeg; j++) {
      float fs = s.f[s.esrc[myStart + j]];
      float e0 = wa0 * fs + wb0 * fi; e0 = e0 > 0.f ? e0 : 0.2f * e0;
      float e1 = wa1 * fs + wb1 * fi; e1 = e1 > 0.f ? e1 : 0.2f * e1;
      float x0 = __expf(e0 - m0), x1 = __expf(e1 - m1);
      ss0 += x0; U0 += x0 * fs;
      ss1 += x1; U1 += x1 * fs;
    }
    S0 = U0 / (ss0 + 1e-9f);
    S1 = U1 / (ss1 + 1e-9f);
    s.u2.a.S0a[t] = S0; s.u2.a.S1a[t] = S1;
  }

  {
    float vals[8] = {fi, fi * fi, S0, S0 * S0, S0 * fi, S1, S1 * S1, S1 * fi};
    #pragma unroll
    for (int d2 = 32; d2 > 0; d2 >>= 1) {
      #pragma unroll
      for (int q = 0; q < 8; q++) vals[q] += __shfl_down(vals[q], d2, 64);
    }
    if (lane == 0) {
      #pragma unroll
      for (int q = 0; q < 8; q++) s.r8[wv][q] = vals[q];
    }
  }
  __syncthreads();
  if (t < 8) s.stat[t] = (s.r8[0][t] + s.r8[1][t] + s.r8[2][t] + s.r8[3][t]) * (1.f / 256.f);
  __syncthreads();
  if (t < 128) {
    float mf = s.stat[0], ef2 = s.stat[1];
    int hh = t >> 6;
    float mS = s.stat[2 + 3 * hh], eS2 = s.stat[3 + 3 * hh], eSf = s.stat[4 + 3 * hh];
    float varS = eS2 - mS * mS, varf = ef2 - mf * mf, cov = eSf - mS * mf;
    float Wv = W1[p * 128 + t], Rv = res1[p * 128 + t], Bv = b1[p * 128 + t];
    float mu  = Wv * mS + Rv * mf + Bv;
    float var = Wv * Wv * varS + Rv * Rv * varf + 2.f * Wv * Rv * cov;
    float gn  = g1[p * 128 + t] * rsqrtf(var + 1e-5f);
    s.u3.a.abg0[t] = gn * Wv;
    s.u3.a.abg1[t] = gn * Rv;
    s.u3.a.abg2[t] = gn * (Bv - mu) + be1[p * 128 + t];
  }
  __syncthreads();

  unsigned resvP[16];   // res2 output, bf16-packed pairs: [(i*2+h2)*2 + (r>>1)]
  f4_t accz[4][2];      // z-half accumulators (32 AGPRs, live across barrier)
  {
    float fm[4], s0m[4], s1m[4];
    #pragma unroll
    for (int i = 0; i < 4; i++) {
      int m = (wv * 4 + i) * 16 + l15;
      fm[i] = s.f[m]; s0m[i] = s.u2.a.S0a[m]; s1m[i] = s.u2.a.S1a[m];
    }
    // ---- group 0: res columns (nt = 2,3) -> pack to resvP, free the accs ---
    {
      f4_t accr[4][2];
      #pragma unroll
      for (int i = 0; i < 4; i++) { accr[i][0] = (f4_t){0,0,0,0}; accr[i][1] = (f4_t){0,0,0,0}; }
      #pragma unroll
      for (int kt = 0; kt < 4; kt++) {
        int cbase = kt * 32 + quad * 8;
        float a0[8], a1[8], a2[8];
        #pragma unroll
        for (int j = 0; j < 8; j++) {
          a0[j] = s.u3.a.abg0[cbase + j]; a1[j] = s.u3.a.abg1[cbase + j]; a2[j] = s.u3.a.abg2[cbase + j];
        }
        s8_t afr[4];
        #pragma unroll
        for (int i = 0; i < 4; i++) {
          float Sm = (kt < 2) ? s0m[i] : s1m[i];
          union { s8_t v; unsigned short u[8]; } fu;
          #pragma unroll
          for (int j = 0; j < 8; j++) {
            float h = fmaxf(fmaf(a0[j], Sm, fmaf(a1[j], fm[i], a2[j])), 0.f);
            fu.u[j] = f2b(h);
          }
          afr[i] = fu.v;
        }
        s8_t bfr0 = *(const s8_t*)&s.u1.wT1[(2 * 16 + l15) * 136 + cbase];
        s8_t bfr1 = *(const s8_t*)&s.u1.wT1[(3 * 16 + l15) * 136 + cbase];
        #pragma unroll
        for (int i = 0; i < 4; i++) {
          accr[i][0] = __builtin_amdgcn_mfma_f32_16x16x32_bf16(afr[i], bfr0, accr[i][0], 0, 0, 0);
          accr[i][1] = __builtin_amdgcn_mfma_f32_16x16x32_bf16(afr[i], bfr1, accr[i][1], 0, 0, 0);
        }
      }
      // fence: finish all group-0 MFMAs, then pack, then let accr die BEFORE
      // any group-1 code is scheduled (prevents live-range overlap -> agpr 64)
      __builtin_amdgcn_sched_barrier(0);
      #pragma unroll
      for (int i = 0; i < 4; i++)
        #pragma unroll
        for (int h2 = 0; h2 < 2; h2++)
          #pragma unroll
          for (int rp = 0; rp < 2; rp++) {
            unsigned lo = f2b(accr[i][h2][rp * 2]);
            unsigned hi = f2b(accr[i][h2][rp * 2 + 1]);
            resvP[(i * 2 + h2) * 2 + rp] = lo | (hi << 16);
          }
      __builtin_amdgcn_sched_barrier(0);
    }
    // ---- group 1: z columns (nt = 0,1) -------------------------------------
    #pragma unroll
    for (int i = 0; i < 4; i++) { accz[i][0] = (f4_t){0,0,0,0}; accz[i][1] = (f4_t){0,0,0,0}; }
    #pragma unroll
    for (int kt = 0; kt < 4; kt++) {
      int cbase = kt * 32 + quad * 8;
      float a0[8], a1[8], a2[8];
      #pragma unroll
      for (int j = 0; j < 8; j++) {
        a0[j] = s.u3.a.abg0[cbase + j]; a1[j] = s.u3.a.abg1[cbase + j]; a2[j] = s.u3.a.abg2[cbase + j];
      }
      s8_t afr[4];
      #pragma unroll
      for (int i = 0; i < 4; i++) {
        float Sm = (kt < 2) ? s0m[i] : s1m[i];
        union { s8_t v; unsigned short u[8]; } fu;
        #pragma unroll
        for (int j = 0; j < 8; j++) {
          float h = fmaxf(fmaf(a0[j], Sm, fmaf(a1[j], fm[i], a2[j])), 0.f);
          fu.u[j] = f2b(h);
        }
        afr[i] = fu.v;
      }
      s8_t bfr0 = *(const s8_t*)&s.u1.wT1[(l15) * 136 + cbase];
      s8_t bfr1 = *(const s8_t*)&s.u1.wT1[(16 + l15) * 136 + cbase];
      #pragma unroll
      for (int i = 0; i < 4; i++) {
        accz[i][0] = __builtin_amdgcn_mfma_f32_16x16x32_bf16(afr[i], bfr0, accz[i][0], 0, 0, 0);
        accz[i][1] = __builtin_amdgcn_mfma_f32_16x16x32_bf16(afr[i], bfr1, accz[i][1], 0, 0, 0);
      }
    }
  }
  // wait for ALL waves to finish reading wT1/abg before overwriting unions
  __syncthreads();
  #pragma unroll
  for (int i = 0; i < 4; i++) {
    int mBase = (wv * 4 + i) * 16 + quad * 4;
    #pragma unroll
    for (int nt = 0; nt < 2; nt++) {
      int col = nt * 16 + l15;
      #pragma unroll
      for (int r = 0; r < 4; r++)
        s.u1.z2[(mBase + r) * 40 + col] = f2b(accz[i][nt][r]);
    }
  }
  __builtin_amdgcn_sched_barrier(0);   // accz dead here; don't extend into staging
  // stage dW1^T (own buffer, stride 36) + small vectors into u3.b
  if (t < 32) { s.u3.b.al2v[t] = al2[p * 32 + t]; s.u3.b.ar2v[t] = ar2[p * 32 + t]; }
  if (t < 128) s.u3.b.dW2v[t] = dW2[p * 128 + t];
  {
    const float* Dg = dW1 + p * 4096;
    #pragma unroll
    for (int q = 0; q < 16; q++) {
      int idx = t + 256 * q;
      int k = idx >> 7, n = idx & 127;
      s.dW1T[n * 36 + k] = f2b(Dg[idx]);
    }
  }
  const float db2v = db2[p];
  __syncthreads();

  {
    const s8_t* zr = (const s8_t*)&s.u1.z2[t * 40];
    float el = 0.f, er = 0.f;
    #pragma unroll
    for (int q = 0; q < 4; q++) {
      s8_t vz = zr[q];
      #pragma unroll
      for (int j = 0; j < 8; j++) {
        float zv = b2f(vz[j]);
        el += zv * s.u3.b.al2v[q * 8 + j];
        er += zv * s.u3.b.ar2v[q * 8 + j];
      }
    }
    s.el2[t] = el; s.er2[t] = er;
  }
  __syncthreads();

  // ---- GAT2 aggregation, two 16-col halves (R7 structure) ------------------
  {
    const float eri = s.er2[t];
    float m = -1e30f;
    for (int j = 0; j < myDeg; j++) {
      float e = s.el2[s.esrc[myStart + j]] + eri;
      e = e > 0.f ? e : 0.2f * e;
      m = fmaxf(m, e);
    }
    float hrow[16];
    float ss = 0.f;
    #pragma unroll
    for (int d2 = 0; d2 < 16; d2++) hrow[d2] = 0.f;
    // pass A: cols 0-15, also accumulate ss (full neighbor sum)
    for (int j = 0; j < myDeg; j++) {
      int sj = s.esrc[myStart + j];
      float e = s.el2[sj] + eri;
      e = e > 0.f ? e : 0.2f * e;
      float x = __expf(e - m);
      ss += x;
      const s8_t* zr = (const s8_t*)&s.u1.z2[sj * 40];
      #pragma unroll
      for (int q = 0; q < 2; q++) {
        s8_t vz = zr[q];
        #pragma unroll
        for (int jj = 0; jj < 8; jj++) hrow[q * 8 + jj] += x * b2f(vz[jj]);
      }
    }
    const float inv = 1.f / (ss + 1e-9f);
    __syncthreads();               // all pass-A gathers done (cols 0-15 free)
    #pragma unroll
    for (int i = 0; i < 4; i++) {
      int mBase = (wv * 4 + i) * 16 + quad * 4;
      #pragma unroll
      for (int r = 0; r < 4; r++)
        s.u1.z2[(mBase + r) * 40 + l15] =
            (unsigned short)(resvP[i * 4 + (r >> 1)] >> ((r & 1) * 16));
    }
    __syncthreads();
    // finalize half0: h = hrow*inv + resv (own row, cols 0-15)
    {
      const s8_t* zr = (const s8_t*)&s.u1.z2[t * 40];
      #pragma unroll
      for (int q = 0; q < 2; q++) {
        s8_t vz = zr[q];
        #pragma unroll
        for (int jj = 0; jj < 8; jj++)
          hrow[q * 8 + jj] = fmaf(hrow[q * 8 + jj], inv, b2f(vz[jj]));
      }
      #pragma unroll
      for (int d2 = 0; d2 < 16; d2++) s.u1.z2[t * 40 + d2] = f2b(hrow[d2]);
    }
    // pass B: cols 16-31 (disjoint from half0 writes; no barrier needed)
    #pragma unroll
    for (int d2 = 0; d2 < 16; d2++) hrow[d2] = 0.f;
    for (int j = 0; j < myDeg; j++) {
      int sj = s.esrc[myStart + j];
      float e = s.el2[sj] + eri;
      e = e > 0.f ? e : 0.2f * e;
      float x = __expf(e - m);
      const s8_t* zr = (const s8_t*)&s.u1.z2[sj * 40];
      #pragma unroll
      for (int q = 0; q < 2; q++) {
        s8_t vz = zr[2 + q];
        #pragma unroll
        for (int jj = 0; jj < 8; jj++) hrow[q * 8 + jj] += x * b2f(vz[jj]);
      }
    }
    __syncthreads();               // all pass-B gathers done (cols 16-31 free)
    #pragma unroll
    for (int i = 0; i < 4; i++) {
      int mBase = (wv * 4 + i) * 16 + quad * 4;
      #pragma unroll
      for (int r = 0; r < 4; r++)
        s.u1.z2[(mBase + r) * 40 + 16 + l15] =
            (unsigned short)(resvP[(i * 2 + 1) * 2 + (r >> 1)] >> ((r & 1) * 16));
    }
    __syncthreads();
    // finalize half1
    {
      const s8_t* zr = (const s8_t*)&s.u1.z2[t * 40];
      #pragma unroll
      for (int q = 0; q < 2; q++) {
        s8_t vz = zr[2 + q];
        #pragma unroll
        for (int jj = 0; jj < 8; jj++)
          hrow[q * 8 + jj] = fmaf(hrow[q * 8 + jj], inv, b2f(vz[jj]));
      }
      #pragma unroll
      for (int d2 = 0; d2 < 16; d2++) s.u1.z2[t * 40 + 16 + d2] = f2b(hrow[d2]);
    }
  }
  __syncthreads();

  {
    int c = t & 31, gq = t >> 5;
    float s1 = 0.f, s2 = 0.f;
    for (int j = 0; j < 32; j++) {
      float vz = b2f((short)s.u1.z2[(gq * 32 + j) * 40 + c]);
      s1 += vz; s2 += vz * vz;
    }
    s.u2.redf[t] = s1; s.u2.redf[256 + t] = s2;
  }
  __syncthreads();
  if (t < 32) {
    float s1 = 0.f, s2 = 0.f;
    #pragma unroll
    for (int q = 0; q < 8; q++) { s1 += s.u2.redf[q * 32 + t]; s2 += s.u2.redf[256 + q * 32 + t]; }
    float mu = s1 * (1.f / 256.f);
    float var = s2 * (1.f / 256.f) - mu * mu;
    float a = g2[p * 32 + t] * rsqrtf(var + 1e-5f);
    s.u4.b.scA[t] = a; s.u4.b.shA[t] = be2[p * 32 + t] - a * mu;
  }
  __syncthreads();
  {
    int c = t & 31, gq = t >> 5;
    float a = s.u4.b.scA[c], bb = s.u4.b.shA[c];
    float s1 = 0.f;
    for (int j = 0; j < 32; j++) {
      int ad = (gq * 32 + j) * 40 + c;
      float vz = b2f((short)s.u1.z2[ad]);
      float hv = fmaxf(a * vz + bb, 0.f);
      s.u1.z2[ad] = f2b(hv);
      s1 += hv;
    }
    s.u2.redf[t] = s1;
  }
  __syncthreads();
  if (t < 32) {
    float s1 = 0.f;
    #pragma unroll
    for (int q = 0; q < 8; q++) s1 += s.u2.redf[q * 32 + t];
    rep_out[g * 32 + t] = s1 * (1.f / 256.f);
  }
  __syncthreads();

  // ---- decoder: grouped MFMA with stats pass + recompute pass --------------
  {
    s8_t afr2[4];
    #pragma unroll
    for (int i = 0; i < 4; i++)
      afr2[i] = *(const s8_t*)&s.u1.z2[((wv * 4 + i) * 16 + l15) * 40 + quad * 8];
    float rAcc[4][4];
    #pragma unroll
    for (int i = 0; i < 4; i++)
      #pragma unroll
      for (int r = 0; r < 4; r++) rAcc[i][r] = 0.f;

    for (int half = 0; half < 2; half++) {
      __syncthreads();
      s.u2.redf[t] = 0.f; s.u2.redf[256 + t] = 0.f;
      __syncthreads();
      // pass 1: stats — grp 0 then grp 1, fenced so acc groups share 32 AGPRs
      {
        f4_t acc2[4][2];
        #pragma unroll
        for (int i = 0; i < 4; i++) { acc2[i][0] = (f4_t){0,0,0,0}; acc2[i][1] = (f4_t){0,0,0,0}; }
        #pragma unroll
        for (int ntl = 0; ntl < 2; ntl++) {
          const s4_t* pr = (const s4_t*)&s.dW1T[(half * 64 + ntl * 16 + l15) * 36 + quad * 8];
          s4_t lo = pr[0], hi = pr[1];
          s8_t bfr = __builtin_shufflevector(lo, hi, 0, 1, 2, 3, 4, 5, 6, 7);
          #pragma unroll
          for (int i = 0; i < 4; i++)
            acc2[i][ntl] = __builtin_amdgcn_mfma_f32_16x16x32_bf16(afr2[i], bfr, acc2[i][ntl], 0, 0, 0);
        }
        #pragma unroll
        for (int ntl = 0; ntl < 2; ntl++) {
          float s1 = 0.f, s2 = 0.f;
          #pragma unroll
          for (int i = 0; i < 4; i++)
            #pragma unroll
            for (int r = 0; r < 4; r++) { float vv = acc2[i][ntl][r]; s1 += vv; s2 += vv * vv; }
          atomicAdd(&s.u2.redf[ntl * 16 + l15], s1);
          atomicAdd(&s.u2.redf[256 + ntl * 16 + l15], s2);
        }
      }
      __builtin_amdgcn_sched_barrier(0);
      {
        f4_t acc2[4][2];
        #pragma unroll
        for (int i = 0; i < 4; i++) { acc2[i][0] = (f4_t){0,0,0,0}; acc2[i][1] = (f4_t){0,0,0,0}; }
        #pragma unroll
        for (int ntl = 0; ntl < 2; ntl++) {
          int nt = 2 + ntl;
          const s4_t* pr = (const s4_t*)&s.dW1T[(half * 64 + nt * 16 + l15) * 36 + quad * 8];
          s4_t lo = pr[0], hi = pr[1];
          s8_t bfr = __builtin_shufflevector(lo, hi, 0, 1, 2, 3, 4, 5, 6, 7);
          #pragma unroll
          for (int i = 0; i < 4; i++)
            acc2[i][ntl] = __builtin_amdgcn_mfma_f32_16x16x32_bf16(afr2[i], bfr, acc2[i][ntl], 0, 0, 0);
        }
        #pragma unroll
        for (int ntl = 0; ntl < 2; ntl++) {
          int nt = 2 + ntl;
          float s1 = 0.f, s2 = 0.f;
          #pragma unroll
          for (int i = 0; i < 4; i++)
            #pragma unroll
            for (int r = 0; r < 4; r++) { float vv = acc2[i][ntl][r]; s1 += vv; s2 += vv * vv; }
          atomicAdd(&s.u2.redf[nt * 16 + l15], s1);
          atomicAdd(&s.u2.redf[256 + nt * 16 + l15], s2);
        }
      }
      __syncthreads();
      if (t < 64) {
        int col = half * 64 + t;
        float mu = s.u2.redf[t] * (1.f / 256.f);
        float var = s.u2.redf[256 + t] * (1.f / 256.f) - mu * mu;
        float a = dg[p * 128 + col] * rsqrtf(var + 1e-5f);
        s.u4.b.dscA[t] = a; s.u4.b.dshA[t] = dbe[p * 128 + col] - a * mu;
      }
      __syncthreads();
      // pass 2: recompute (bit-identical) + apply BN/relu and fold dW2
      {
        f4_t acc2[4][2];
        #pragma unroll
        for (int i = 0; i < 4; i++) { acc2[i][0] = (f4_t){0,0,0,0}; acc2[i][1] = (f4_t){0,0,0,0}; }
        #pragma unroll
        for (int ntl = 0; ntl < 2; ntl++) {
          const s4_t* pr = (const s4_t*)&s.dW1T[(half * 64 + ntl * 16 + l15) * 36 + quad * 8];
          s4_t lo = pr[0], hi = pr[1];
          s8_t bfr = __builtin_shufflevector(lo, hi, 0, 1, 2, 3, 4, 5, 6, 7);
          #pragma unroll
          for (int i = 0; i < 4; i++)
            acc2[i][ntl] = __builtin_amdgcn_mfma_f32_16x16x32_bf16(afr2[i], bfr, acc2[i][ntl], 0, 0, 0);
        }
        #pragma unroll
        for (int ntl = 0; ntl < 2; ntl++) {
          int cl = ntl * 16 + l15;
          float a = s.u4.b.dscA[cl], bb = s.u4.b.dshA[cl], w2 = s.u3.b.dW2v[half * 64 + cl];
          #pragma unroll
          for (int i = 0; i < 4; i++)
            #pragma unroll
            for (int r = 0; r < 4; r++) {
              float dv = fmaxf(a * acc2[i][ntl][r] + bb, 0.f);
              rAcc[i][r] += dv * w2;
            }
        }
      }
      __builtin_amdgcn_sched_barrier(0);
      {
        f4_t acc2[4][2];
        #pragma unroll
        for (int i = 0; i < 4; i++) { acc2[i][0] = (f4_t){0,0,0,0}; acc2[i][1] = (f4_t){0,0,0,0}; }
        #pragma unroll
        for (int ntl = 0; ntl < 2; ntl++) {
          int nt = 2 + ntl;
          const s4_t* pr = (const s4_t*)&s.dW1T[(half * 64 + nt * 16 + l15) * 36 + quad * 8];
          s4_t lo = pr[0], hi = pr[1];
          s8_t bfr = __builtin_shufflevector(lo, hi, 0, 1, 2, 3, 4, 5, 6, 7);
          #pragma unroll
          for (int i = 0; i < 4; i++)
            acc2[i][ntl] = __builtin_amdgcn_mfma_f32_16x16x32_bf16(afr2[i], bfr, acc2[i][ntl], 0, 0, 0);
        }
        #pragma unroll
        for (int ntl = 0; ntl < 2; ntl++) {
          int cl = (2 + ntl) * 16 + l15;
          float a = s.u4.b.dscA[cl], bb = s.u4.b.dshA[cl], w2 = s.u3.b.dW2v[half * 64 + cl];
          #pragma unroll
          for (int i = 0; i < 4; i++)
            #pragma unroll
            for (int r = 0; r < 4; r++) {
              float dv = fmaxf(a * acc2[i][ntl][r] + bb, 0.f);
              rAcc[i][r] += dv * w2;
            }
        }
      }
    }
    #pragma unroll
    for (int off = 1; off < 16; off <<= 1)
      #pragma unroll
      for (int i = 0; i < 4; i++)
        #pragma unroll
        for (int r = 0; r < 4; r++) rAcc[i][r] += __shfl_xor(rAcc[i][r], off, 64);
    if (l15 == 0) {
      float sq = 0.f;
      #pragma unroll
      for (int i = 0; i < 4; i++)
        #pragma unroll
        for (int r = 0; r < 4; r++) {
          int m = (wv * 4 + i) * 16 + quad * 4 + r;
          float diff = rAcc[i][r] + db2v - s.f[m];
          sq += diff * diff;
        }
      atomicAdd(&s.rlacc, sq);
    }
  }
  __syncthreads();
  if (t == 0) rlp_out[g] = s.rlacc;
}

// ---------------------------------------------------------------------------
// ft matmul + Abar build. Grid = 9 blocks (block 8 = Abar, concurrent).
// ---------------------------------------------------------------------------
__global__ __launch_bounds__(256) void ft_mm(
    const float* __restrict__ orig, const float* __restrict__ rep,
    const float* __restrict__ ftW, float* __restrict__ hpre,
    const int* __restrict__ ps, const int* __restrict__ pd,
    const int* __restrict__ mask, unsigned short* __restrict__ abar)
{
  const int t = threadIdx.x;

  if (blockIdx.x == 8) {
    __shared__ int aB[128 * 128];
    __shared__ int co[128], ci[128];
    __shared__ float facs[128], facd[128];
    for (int idx = t; idx < 16384; idx += 256) aB[idx] = 0;
    if (t < 128) { co[t] = 0; ci[t] = 0; }
    __syncthreads();
    for (int e = t; e < EPG_; e += 256) {
      int sN = ps[e], d = pd[e];
      atomicAdd(&co[sN], 1);
      atomicAdd(&ci[d], 1);
      atomicAdd(&aB[d * 128 + sN], 1);
    }
    __syncthreads();
    if (t < 128) {
      float mk = (float)mask[t];
      int da = co[t] > 1 ? co[t] : 1;
      int db = ci[t] > 1 ? ci[t] : 1;
      facs[t] = mk * rsqrtf((float)da);
      facd[t] = mk * rsqrtf((float)db);
    }
    __syncthreads();
    for (int idx = t; idx < 16384; idx += 256) {
      int d = idx >> 7, sN = idx & 127;
      abar[idx] = f2b((float)aB[idx] * facd[d] * facs[sN]);
    }
    return;
  }

  const int wv = t >> 6, lane = t & 63;
  const int l15 = lane & 15, quad = lane >> 4;
  const int m = blockIdx.x * 16 + l15;

  f4_t acc[2];
  acc[0] = (f4_t){0.f, 0.f, 0.f, 0.f};
  acc[1] = (f4_t){0.f, 0.f, 0.f, 0.f};
  for (int kt = 0; kt < 24; kt++) {
    int k0 = kt * 32 + quad * 8;
    const float* px = (k0 < 256) ? (orig + m * 256 + k0) : (rep + m * 512 + (k0 - 256));
    float4 xa = ((const float4*)px)[0];
    float4 xb = ((const float4*)px)[1];
    union { s8_t v; unsigned short u[8]; } fu;
    fu.u[0] = f2b(xa.x); fu.u[1] = f2b(xa.y); fu.u[2] = f2b(xa.z); fu.u[3] = f2b(xa.w);
    fu.u[4] = f2b(xb.x); fu.u[5] = f2b(xb.y); fu.u[6] = f2b(xb.z); fu.u[7] = f2b(xb.w);
    #pragma unroll
    for (int nt = 0; nt < 2; nt++) {
      int col = wv * 32 + nt * 16 + l15;
      union { s8_t v; unsigned short u[8]; } bu;
      #pragma unroll
      for (int j = 0; j < 8; j++) bu.u[j] = f2b(ftW[(k0 + j) * 128 + col]);
      acc[nt] = __builtin_amdgcn_mfma_f32_16x16x32_bf16(fu.v, bu.v, acc[nt], 0, 0, 0);
    }
  }
  #pragma unroll
  for (int nt = 0; nt < 2; nt++) {
    int col = wv * 32 + nt * 16 + l15;
    #pragma unroll
    for (int r = 0; r < 4; r++)
      hpre[(blockIdx.x * 16 + quad * 4 + r) * 128 + col] = acc[nt][r];
  }
}

// ---------------------------------------------------------------------------
// Fused patient stage: ONE block, 1024 threads (16 waves). (unchanged)
// ---------------------------------------------------------------------------
struct SmemB {
  __align__(16) unsigned short arow[128 * 136];  // Abar bf16, rows=dst
  __align__(16) unsigned short hT[128 * 136];    // h^T bf16 [feature][patient]
  union {
    struct {
      union {
        __align__(16) unsigned short wT[128 * 136]; // B^T staging (gcW/c1W)
        float zF[128 * 68];                         // cls pre-LN
      } w;
      __align__(16) unsigned short aggB[128 * 136]; // agg / hsum A-operand
    } mm;
  } u;
  float redA[1024], redB[1024];
  float scB[128], shB[128];
};

__global__ __launch_bounds__(1024) void k_patient(
    const float* __restrict__ hpre, const unsigned short* __restrict__ abar,
    const float* __restrict__ ftg, const float* __restrict__ ftbe,
    const float* __restrict__ gcW, const float* __restrict__ gbng, const float* __restrict__ gbnbe,
    const float* __restrict__ c1W, const float* __restrict__ c1b,
    const float* __restrict__ lng, const float* __restrict__ lnbe,
    const float* __restrict__ c2W, const float* __restrict__ c2b,
    const float* __restrict__ rlp, float* __restrict__ out)
{
  __shared__ SmemB s;
  const int t = threadIdx.x;
  const int w = t >> 6, lane = t & 63;
  const int l15 = lane & 15, quad = lane >> 4;
  const int mb = w & 7, nb = (w >> 3) * 64;

  for (int idx = t; idx < 16384; idx += 1024) {
    int d = idx >> 7, sN = idx & 127;
    s.arow[d * 136 + sN] = abar[idx];
  }

  f4_t acc[4];
  #pragma unroll
  for (int nt = 0; nt < 4; nt++) {
    int col = nb + nt * 16 + l15;
    #pragma unroll
    for (int r = 0; r < 4; r++)
      acc[nt][r] = hpre[(mb * 16 + quad * 4 + r) * 128 + col];
  }

  float hR[16], hsumR[16];
  {
    #pragma unroll
    for (int nt = 0; nt < 4; nt++) {
      float s1 = acc[nt][0] + acc[nt][1] + acc[nt][2] + acc[nt][3];
      float s2 = acc[nt][0]*acc[nt][0] + acc[nt][1]*acc[nt][1] + acc[nt][2]*acc[nt][2] + acc[nt][3]*acc[nt][3];
      s1 += __shfl_xor(s1, 16, 64); s1 += __shfl_xor(s1, 32, 64);
      s2 += __shfl_xor(s2, 16, 64); s2 += __shfl_xor(s2, 32, 64);
      if (quad == 0) {
        s.redA[mb * 128 + nb + nt * 16 + l15] = s1;
        s.redB[mb * 128 + nb + nt * 16 + l15] = s2;
      }
    }
    __syncthreads();
    if (t < 128) {
      float a1 = 0.f, a2 = 0.f;
      #pragma unroll
      for (int q = 0; q < 8; q++) { a1 += s.redA[q * 128 + t]; a2 += s.redB[q * 128 + t]; }
      float mu = a1 * (1.f / 128.f), var = a2 * (1.f / 128.f) - mu * mu;
      float a = ftg[t] * rsqrtf(var + 1e-5f);
      s.scB[t] = a; s.shB[t] = ftbe[t] - a * mu;
    }
    __syncthreads();
    #pragma unroll
    for (int nt = 0; nt < 4; nt++) {
      int col = nb + nt * 16 + l15;
      float a = s.scB[col], bb = s.shB[col];
      #pragma unroll
      for (int r = 0; r < 4; r++) {
        int row = mb * 16 + quad * 4 + r;
        float hv = fmaxf(a * acc[nt][r] + bb, 0.f);
        hR[nt * 4 + r] = hv; hsumR[nt * 4 + r] = hv;
        s.hT[col * 136 + row] = f2b(hv);
      }
    }
  }
  __syncthreads();

  for (int layer = 0; layer < 3; layer++) {
    #pragma unroll
    for (int q = 0; q < 16; q++) {
      int idx = t + 1024 * q;
      int kk = idx >> 7, n = idx & 127;
      s.u.mm.w.wT[n * 136 + kk] = f2b(gcW[layer * 16384 + kk * 128 + n]);
    }
    f4_t ag[4];
    #pragma unroll
    for (int nt = 0; nt < 4; nt++) ag[nt] = (f4_t){0.f, 0.f, 0.f, 0.f};
    #pragma unroll
    for (int ks = 0; ks < 4; ks++) {
      s8_t afr = *(const s8_t*)&s.arow[(mb * 16 + l15) * 136 + ks * 32 + quad * 8];
      #pragma unroll
      for (int nt = 0; nt < 4; nt++) {
        s8_t bfr = *(const s8_t*)&s.hT[(nb + nt * 16 + l15) * 136 + ks * 32 + quad * 8];
        ag[nt] = __builtin_amdgcn_mfma_f32_16x16x32_bf16(afr, bfr, ag[nt], 0, 0, 0);
      }
    }
    #pragma unroll
    for (int nt = 0; nt < 4; nt++) {
      int col = nb + nt * 16 + l15;
      #pragma unroll
      for (int r = 0; r < 4; r++)
        s.u.mm.aggB[(mb * 16 + quad * 4 + r) * 136 + col] = f2b(ag[nt][r]);
    }
    __syncthreads();
    f4_t oc[4];
    #pragma unroll
    for (int nt = 0; nt < 4; nt++) oc[nt] = (f4_t){0.f, 0.f, 0.f, 0.f};
    #pragma unroll
    for (int ks = 0; ks < 4; ks++) {
      s8_t afr = *(const s8_t*)&s.u.mm.aggB[(mb * 16 + l15) * 136 + ks * 32 + quad * 8];
      #pragma unroll
      for (int nt = 0; nt < 4; nt++) {
        s8_t bfr = *(const s8_t*)&s.u.mm.w.wT[(nb + nt * 16 + l15) * 136 + ks * 32 + quad * 8];
        oc[nt] = __builtin_amdgcn_mfma_f32_16x16x32_bf16(afr, bfr, oc[nt], 0, 0, 0);
      }
    }
    #pragma unroll
    for (int nt = 0; nt < 4; nt++) {
      float s1 = oc[nt][0] + oc[nt][1] + oc[nt][2] + oc[nt][3];
      float s2 = oc[nt][0]*oc[nt][0] + oc[nt][1]*oc[nt][1] + oc[nt][2]*oc[nt][2] + oc[nt][3]*oc[nt][3];
      s1 += __shfl_xor(s1, 16, 64); s1 += __shfl_xor(s1, 32, 64);
      s2 += __shfl_xor(s2, 16, 64); s2 += __shfl_xor(s2, 32, 64);
      if (quad == 0) {
        s.redA[mb * 128 + nb + nt * 16 + l15] = s1;
        s.redB[mb * 128 + nb + nt * 16 + l15] = s2;
      }
    }
    __syncthreads();
    if (t < 128) {
      float a1 = 0.f, a2 = 0.f;
      #pragma unroll
      for (int q = 0; q < 8; q++) { a1 += s.redA[q * 128 + t]; a2 += s.redB[q * 128 + t]; }
      float mu = a1 * (1.f / 128.f), var = a2 * (1.f / 128.f) - mu * mu;
      float a = gbng[layer * 128 + t] * rsqrtf(var + 1e-5f);
      s.scB[t] = a; s.shB[t] = gbnbe[layer * 128 + t] - a * mu;
    }
    __syncthreads();
    #pragma unroll
    for (int nt = 0; nt < 4; nt++) {
      int col = nb + nt * 16 + l15;
      float a = s.scB[col], bb = s.shB[col];
      #pragma unroll
      for (int r = 0; r < 4; r++) {
        int row = mb * 16 + quad * 4 + r;
        float hn = fmaxf(a * oc[nt][r] + bb, 0.f) + hR[nt * 4 + r];
        hR[nt * 4 + r] = hn;
        hsumR[nt * 4 + r] += hn;
        s.hT[col * 136 + row] = f2b(hn);
      }
    }
    __syncthreads();
  }

  #pragma unroll
  for (int nt = 0; nt < 4; nt++) {
    int col = nb + nt * 16 + l15;
    #pragma unroll
    for (int r = 0; r < 4; r++)
      s.u.mm.aggB[(mb * 16 + quad * 4 + r) * 136 + col] = f2b(hsumR[nt * 4 + r] * 0.25f);
  }
  #pragma unroll
  for (int q = 0; q < 8; q++) {
    int idx = t + 1024 * q;
    int n = idx & 63, kk = idx >> 6;
    s.u.mm.w.wT[n * 136 + kk] = f2b(c1W[kk * 64 + n]);
  }
  __syncthreads();
  {
    const int nb2 = (w >> 3) * 32;
    f4_t zc[2];
    #pragma unroll
    for (int nt = 0; nt < 2; nt++) zc[nt] = (f4_t){0.f, 0.f, 0.f, 0.f};
    #pragma unroll
    for (int ks = 0; ks < 4; ks++) {
      s8_t afr = *(const s8_t*)&s.u.mm.aggB[(mb * 16 + l15) * 136 + ks * 32 + quad * 8];
      #pragma unroll
      for (int nt = 0; nt < 2; nt++) {
        s8_t bfr = *(const s8_t*)&s.u.mm.w.wT[(nb2 + nt * 16 + l15) * 136 + ks * 32 + quad * 8];
        zc[nt] = __builtin_amdgcn_mfma_f32_16x16x32_bf16(afr, bfr, zc[nt], 0, 0, 0);
      }
    }
    __syncthreads();
    #pragma unroll
    for (int nt = 0; nt < 2; nt++) {
      int col = nb2 + nt * 16 + l15;
      #pragma unroll
      for (int r = 0; r < 4; r++)
        s.u.mm.w.zF[(mb * 16 + quad * 4 + r) * 68 + col] = zc[nt][r] + c1b[col];
    }
  }
  __syncthreads();
  if (t < 128) {
    float s1 = 0.f, s2 = 0.f;
    #pragma unroll
    for (int j = 0; j < 64; j++) { float zv = s.u.mm.w.zF[t * 68 + j]; s1 += zv; s2 += zv * zv; }
    float mu = s1 * (1.f / 64.f);
    float var = s2 * (1.f / 64.f) - mu * mu;
    float rs = rsqrtf(var + 1e-5f);
    float l0 = 0.f, l1 = 0.f;
    #pragma unroll
    for (int j = 0; j < 64; j++) {
      float zv = s.u.mm.w.zF[t * 68 + j];
      float zn = fmaxf(lng[j] * (zv - mu) * rs + lnbe[j], 0.f);
      l0 += zn * c2W[j * 2];
      l1 += zn * c2W[j * 2 + 1];
    }
    out[t * 2]     = l0 + c2b[0];
    out[t * 2 + 1] = l1 + c2b[1];
  }

  {
    float r = rlp[t] + rlp[t + 1024];
    #pragma unroll
    for (int off = 32; off > 0; off >>= 1) r += __shfl_down(r, off, 64);
    if (lane == 0) s.redA[w] = r;
  }
  __syncthreads();
  if (t == 0) {
    float tot = 0.f;
    #pragma unroll
    for (int i = 0; i < 16; i++) tot += s.redA[i];
    out[256] = tot * (1.f / (256.f * 2048.f));
  }
}

// ---------------------------------------------------------------------------
extern "C" void kernel_launch(void* const* d_in, const int* in_sizes, int n_in,
                              void* d_out, int out_size, void* d_ws, size_t ws_size,
                              hipStream_t stream) {
  (void)in_sizes; (void)n_in; (void)out_size; (void)ws_size;
  const float* plane_feat  = (const float*)d_in[0];
  const int*   plane_src   = (const int*)d_in[1];
  const int*   plane_dst   = (const int*)d_in[2];
  const int*   patient_src = (const int*)d_in[3];
  const int*   patient_dst = (const int*)d_in[4];
  const float* orig        = (const float*)d_in[5];
  const int*   mask        = (const int*)d_in[6];
  const float* W1   = (const float*)d_in[7];
  const float* al1  = (const float*)d_in[8];
  const float* ar1  = (const float*)d_in[9];
  const float* res1 = (const float*)d_in[10];
  const float* b1   = (const float*)d_in[11];
  const float* g1   = (const float*)d_in[12];
  const float* be1  = (const float*)d_in[13];
  const float* W2   = (const float*)d_in[14];
  const float* al2  = (const float*)d_in[15];
  const float* ar2  = (const float*)d_in[16];
  const float* res2 = (const float*)d_in[17];
  const float* g2   = (const float*)d_in[19];
  const float* be2  = (const float*)d_in[20];
  const float* dW1  = (const float*)d_in[21];
  const float* dg   = (const float*)d_in[23];
  const float* dbe  = (const float*)d_in[24];
  const float* dW2  = (const float*)d_in[25];
  const float* db2  = (const float*)d_in[26];
  const float* ftW  = (const float*)d_in[27];
  const float* ftg  = (const float*)d_in[29];
  const float* ftbe = (const float*)d_in[30];
  const float* gcW  = (const float*)d_in[31];
  const float* gbng = (const float*)d_in[33];
  const float* gbnbe= (const float*)d_in[34];
  const float* c1W  = (const float*)d_in[35];
  const float* c1b  = (const float*)d_in[36];
  const float* lng  = (const float*)d_in[37];
  const float* lnbe = (const float*)d_in[38];
  const float* c2W  = (const float*)d_in[39];
  const float* c2b  = (const float*)d_in[40];

  float* ws   = (float*)d_ws;
  float* rep  = ws;                                   // [2048][32] = 65536 floats
  float* hpre = ws + 65536;                           // [128][128] ft matmul out
  unsigned short* abar = (unsigned short*)(ws + 81920); // [128][128] bf16 Abar
  float* rlp  = ws + 90112;                           // [2048] per-block rloss
  float* outp = (float*)d_out;

  plane_enc<<<2048, 256, 0, stream>>>(plane_feat, plane_src, plane_dst,
      W1, al1, ar1, res1, b1, g1, be1, W2, al2, ar2, res2, g2, be2,
      dW1, dg, dbe, dW2, db2, rep, rlp);
  ft_mm<<<9, 256, 0, stream>>>(orig, rep, ftW, hpre,
      patient_src, patient_dst, mask, abar);
  k_patient<<<1, 1024, 0, stream>>>(hpre, abar, ftg, ftbe,
      gcW, gbng, gbnbe, c1W, c1b, lng, lnbe, c2W, c2b, rlp, outp);
}

// Round 9
// 312.529 us; speedup vs baseline: 1.0411x; 1.0411x over previous
//
#include <hip/hip_runtime.h>

#define B_    128
#define P_    16
#define NP_   256
#define EP_   1280
#define EPG_  2048
#define ODIM_ 256
#define NH_   128

typedef __attribute__((ext_vector_type(8))) short s8_t;
typedef __attribute__((ext_vector_type(4))) short s4_t;
typedef __attribute__((ext_vector_type(4))) float f4_t;

__device__ __forceinline__ unsigned short f2b(float x) {
  unsigned u = __builtin_bit_cast(unsigned, x);
  u = (u + 0x7fffu + ((u >> 16) & 1u)) >> 16;
  return (unsigned short)u;
}
__device__ __forceinline__ float b2f(short x) {
  unsigned u = ((unsigned)(unsigned short)x) << 16;
  return __builtin_bit_cast(float, u);
}

// ---------------------------------------------------------------------------
// Stage A: one block (256 thr) per plane graph (2048).
// R12 = R11 resubmit (R8 bench was an infra failure, kernel never measured).
// Proven R5/R8 body: (256,3), 84 arch + 64 acc VGPR, zero spill. The (256,4)
// line is dead (R4,R6/R7,R9,R10 all spill-cancelled). 3 blocks/CU is this
// structure's operating point.
// ---------------------------------------------------------------------------
struct SmemA {
  float f[256];                                   // whole kernel (recon at end)
  union {
    __align__(16) unsigned short wT1[64 * 136];   // P1-P3: (W2|res2)^T staging
    __align__(16) unsigned short z2[256 * 40];    // P3-P7: z / h matrix
  } u1;
  __align__(16) unsigned short dW1T[128 * 36];    // P4-P7: dW1^T, stride 36
  union {
    struct { float S0a[256]; float S1a[256]; } a; // P1-P3
    float redf[512];                              // P6-P7
  } u2;
  float el2[256], er2[256];                       // P1 then P4-P5
  union {
    struct { float abg0[128], abg1[128], abg2[128]; } a;  // P2-P3
    struct { float al2v[32], ar2v[32], dW2v[128]; } b;    // P4-P7
  } u3;
  union {
    int cnt[256];                                 // P0
    struct { float scA[32], shA[32], dscA[64], dshA[64]; } b; // P6-P7
  } u4;
  unsigned short esrc[1280];                      // P0-P5
  int wtot[4];
  float r8[4][8]; float stat[8]; float wA[2], wB[2];
  float rlacc;
};

__global__ __launch_bounds__(256, 3) void plane_enc(
    const float* __restrict__ feat, const int* __restrict__ esrcg, const int* __restrict__ edstg,
    const float* __restrict__ W1, const float* __restrict__ al1, const float* __restrict__ ar1,
    const float* __restrict__ res1, const float* __restrict__ b1, const float* __restrict__ g1,
    const float* __restrict__ be1,
    const float* __restrict__ W2, const float* __restrict__ al2, const float* __restrict__ ar2,
    const float* __restrict__ res2, const float* __restrict__ g2, const float* __restrict__ be2,
    const float* __restrict__ dW1, const float* __restrict__ dg, const float* __restrict__ dbe,
    const float* __restrict__ dW2, const float* __restrict__ db2,
    float* __restrict__ rep_out, float* __restrict__ rlp_out)
{
  __shared__ SmemA s;
  const int g = blockIdx.x;
  const int p = g & 15;
  const int t = threadIdx.x;
  const int lane = t & 63, wv = t >> 6;
  const int l15 = lane & 15, quad = lane >> 4;

  s.f[t] = feat[g * NP_ + t];
  if (t == 0) s.rlacc = 0.f;
  s.u4.cnt[t] = 0;
  __syncthreads();

  const int* gs = esrcg + g * EP_;
  const int* gd = edstg + g * EP_;
  for (int k = t; k < EP_; k += 256) atomicAdd(&s.u4.cnt[gd[k]], 1);
  __syncthreads();
  int v = s.u4.cnt[t];
  int incl = v;
  #pragma unroll
  for (int off = 1; off < 64; off <<= 1) {
    int n = __shfl_up(incl, off, 64);
    if (lane >= off) incl += n;
  }
  if (lane == 63) s.wtot[wv] = incl;
  __syncthreads();
  int woff = 0;
  for (int w = 0; w < wv; w++) woff += s.wtot[w];
  const int myStart = woff + incl - v;
  const int myDeg = v;
  __syncthreads();
  s.u4.cnt[t] = myStart;
  __syncthreads();
  for (int k = t; k < EP_; k += 256) {
    int d = gd[k];
    int pos = atomicAdd(&s.u4.cnt[d], 1);
    s.esrc[pos] = (unsigned short)gs[k];
  }
  {
    const float* W2g = W2 + p * 4096;
    const float* Rg  = res2 + p * 4096;
    for (int q = 0; q < 16; q++) {
      int idx = t + 256 * q;
      int k = idx >> 5, n = idx & 31;
      s.u1.wT1[n * 136 + k]        = f2b(W2g[idx]);
      s.u1.wT1[(n + 32) * 136 + k] = f2b(Rg[idx]);
    }
  }
  if (t < 128) {
    float w1v = W1[p * 128 + t];
    s.el2[t] = w1v * al1[p * 128 + t];
    s.er2[t] = w1v * ar1[p * 128 + t];
  }
  __syncthreads();
  if (t < 2) {
    float a = 0.f, bq = 0.f;
    for (int d2 = 0; d2 < 64; d2++) { a += s.el2[t * 64 + d2]; bq += s.er2[t * 64 + d2]; }
    s.wA[t] = a; s.wB[t] = bq;
  }
  __syncthreads();

  const float fi = s.f[t];
  float S0, S1;
  {
    const float wa0 = s.wA[0], wb0 = s.wB[0], wa1 = s.wA[1], wb1 = s.wB[1];
    float m0 = -1e30f, m1 = -1e30f;
    for (int j = 0; j < myDeg; j++) {
      float fs = s.f[s.esrc[myStart + j]];
      float e0 = wa0 * fs + wb0 * fi; e0 = e0 > 0.f ? e0 : 0.2f * e0;
      float e1 = wa1 * fs + wb1 * fi; e1 = e1 > 0.f ? e1 : 0.2f * e1;
      m0 = fmaxf(m0, e0); m1 = fmaxf(m1, e1);
    }
    float ss0 = 0.f, ss1 = 0.f, U0 = 0.f, U1 = 0.f;
    for (int j = 0; j < myDeg; j++) {
      float fs = s.f[s.esrc[myStart + j]];
      float e0 = wa0 * fs + wb0 * fi; e0 = e0 > 0.f ? e0 : 0.2f * e0;
      float e1 = wa1 * fs + wb1 * fi; e1 = e1 > 0.f ? e1 : 0.2f * e1;
      float x0 = __expf(e0 - m0), x1 = __expf(e1 - m1);
      ss0 += x0; U0 += x0 * fs;
      ss1 += x1; U1 += x1 * fs;
    }
    S0 = U0 / (ss0 + 1e-9f);
    S1 = U1 / (ss1 + 1e-9f);
    s.u2.a.S0a[t] = S0; s.u2.a.S1a[t] = S1;
  }

  {
    float vals[8] = {fi, fi * fi, S0, S0 * S0, S0 * fi, S1, S1 * S1, S1 * fi};
    #pragma unroll
    for (int d2 = 32; d2 > 0; d2 >>= 1) {
      #pragma unroll
      for (int q = 0; q < 8; q++) vals[q] += __shfl_down(vals[q], d2, 64);
    }
    if (lane == 0) {
      #pragma unroll
      for (int q = 0; q < 8; q++) s.r8[wv][q] = vals[q];
    }
  }
  __syncthreads();
  if (t < 8) s.stat[t] = (s.r8[0][t] + s.r8[1][t] + s.r8[2][t] + s.r8[3][t]) * (1.f / 256.f);
  __syncthreads();
  if (t < 128) {
    float mf = s.stat[0], ef2 = s.stat[1];
    int hh = t >> 6;
    float mS = s.stat[2 + 3 * hh], eS2 = s.stat[3 + 3 * hh], eSf = s.stat[4 + 3 * hh];
    float varS = eS2 - mS * mS, varf = ef2 - mf * mf, cov = eSf - mS * mf;
    float Wv = W1[p * 128 + t], Rv = res1[p * 128 + t], Bv = b1[p * 128 + t];
    float mu  = Wv * mS + Rv * mf + Bv;
    float var = Wv * Wv * varS + Rv * Rv * varf + 2.f * Wv * Rv * cov;
    float gn  = g1[p * 128 + t] * rsqrtf(var + 1e-5f);
    s.u3.a.abg0[t] = gn * Wv;
    s.u3.a.abg1[t] = gn * Rv;
    s.u3.a.abg2[t] = gn * (Bv - mu) + be1[p * 128 + t];
  }
  __syncthreads();

  float resv[32];
  {
    f4_t accum[4][4];
    #pragma unroll
    for (int i = 0; i < 4; i++)
      #pragma unroll
      for (int nt = 0; nt < 4; nt++) accum[i][nt] = (f4_t){0.f, 0.f, 0.f, 0.f};

    float fm[4], s0m[4], s1m[4];
    #pragma unroll
    for (int i = 0; i < 4; i++) {
      int m = (wv * 4 + i) * 16 + l15;
      fm[i] = s.f[m]; s0m[i] = s.u2.a.S0a[m]; s1m[i] = s.u2.a.S1a[m];
    }
    #pragma unroll
    for (int kt = 0; kt < 4; kt++) {
      int cbase = kt * 32 + quad * 8;
      float a0[8], a1[8], a2[8];
      #pragma unroll
      for (int j = 0; j < 8; j++) {
        a0[j] = s.u3.a.abg0[cbase + j]; a1[j] = s.u3.a.abg1[cbase + j]; a2[j] = s.u3.a.abg2[cbase + j];
      }
      s8_t afr[4];
      #pragma unroll
      for (int i = 0; i < 4; i++) {
        float Sm = (kt < 2) ? s0m[i] : s1m[i];
        union { s8_t v; unsigned short u[8]; } fu;
        #pragma unroll
        for (int j = 0; j < 8; j++) {
          float h = fmaxf(fmaf(a0[j], Sm, fmaf(a1[j], fm[i], a2[j])), 0.f);
          fu.u[j] = f2b(h);
        }
        afr[i] = fu.v;
      }
      s8_t bfr[4];
      #pragma unroll
      for (int nt = 0; nt < 4; nt++)
        bfr[nt] = *(const s8_t*)&s.u1.wT1[(nt * 16 + l15) * 136 + cbase];
      #pragma unroll
      for (int i = 0; i < 4; i++)
        #pragma unroll
        for (int nt = 0; nt < 4; nt++)
          accum[i][nt] = __builtin_amdgcn_mfma_f32_16x16x32_bf16(afr[i], bfr[nt], accum[i][nt], 0, 0, 0);
    }
    // accum fully in registers; wait for ALL waves to finish reading wT1/abg
    // before overwriting the union regions (z2 over wT1, al2v/dW2v over abg).
    __syncthreads();
    #pragma unroll
    for (int i = 0; i < 4; i++) {
      int mBase = (wv * 4 + i) * 16 + quad * 4;
      #pragma unroll
      for (int nt = 0; nt < 2; nt++) {
        int col = nt * 16 + l15;
        #pragma unroll
        for (int r = 0; r < 4; r++)
          s.u1.z2[(mBase + r) * 40 + col] = f2b(accum[i][nt][r]);
      }
      #pragma unroll
      for (int h2 = 0; h2 < 2; h2++)
        #pragma unroll
        for (int r = 0; r < 4; r++)
          resv[(i * 2 + h2) * 4 + r] = accum[i][2 + h2][r];
    }
  }
  // stage dW1^T (own buffer, stride 36) + small vectors into u3.b
  if (t < 32) { s.u3.b.al2v[t] = al2[p * 32 + t]; s.u3.b.ar2v[t] = ar2[p * 32 + t]; }
  if (t < 128) s.u3.b.dW2v[t] = dW2[p * 128 + t];
  {
    const float* Dg = dW1 + p * 4096;
    #pragma unroll
    for (int q = 0; q < 16; q++) {
      int idx = t + 256 * q;
      int k = idx >> 7, n = idx & 127;
      s.dW1T[n * 36 + k] = f2b(Dg[idx]);
    }
  }
  const float db2v = db2[p];
  __syncthreads();

  {
    const s8_t* zr = (const s8_t*)&s.u1.z2[t * 40];
    float el = 0.f, er = 0.f;
    #pragma unroll
    for (int q = 0; q < 4; q++) {
      s8_t vz = zr[q];
      #pragma unroll
      for (int j = 0; j < 8; j++) {
        float zv = b2f(vz[j]);
        el += zv * s.u3.b.al2v[q * 8 + j];
        er += zv * s.u3.b.ar2v[q * 8 + j];
      }
    }
    s.el2[t] = el; s.er2[t] = er;
  }
  __syncthreads();

  float hrow[32];
  {
    const float eri = s.er2[t];
    float m = -1e30f;
    for (int j = 0; j < myDeg; j++) {
      float e = s.el2[s.esrc[myStart + j]] + eri;
      e = e > 0.f ? e : 0.2f * e;
      m = fmaxf(m, e);
    }
    float ss = 0.f;
    #pragma unroll
    for (int d2 = 0; d2 < 32; d2++) hrow[d2] = 0.f;
    for (int j = 0; j < myDeg; j++) {
      int sj = s.esrc[myStart + j];
      float e = s.el2[sj] + eri;
      e = e > 0.f ? e : 0.2f * e;
      float x = __expf(e - m);
      ss += x;
      const s8_t* zr = (const s8_t*)&s.u1.z2[sj * 40];
      #pragma unroll
      for (int q = 0; q < 4; q++) {
        s8_t vz = zr[q];
        #pragma unroll
        for (int jj = 0; jj < 8; jj++) hrow[q * 8 + jj] += x * b2f(vz[jj]);
      }
    }
    float inv = 1.f / (ss + 1e-9f);
    #pragma unroll
    for (int d2 = 0; d2 < 32; d2++) hrow[d2] *= inv;
  }
  __syncthreads();
  #pragma unroll
  for (int i = 0; i < 4; i++) {
    int mBase = (wv * 4 + i) * 16 + quad * 4;
    #pragma unroll
    for (int h2 = 0; h2 < 2; h2++) {
      int col = h2 * 16 + l15;
      #pragma unroll
      for (int r = 0; r < 4; r++)
        s.u1.z2[(mBase + r) * 40 + col] = f2b(resv[(i * 2 + h2) * 4 + r]);
    }
  }
  __syncthreads();
  {
    const s8_t* zr = (const s8_t*)&s.u1.z2[t * 40];
    #pragma unroll
    for (int q = 0; q < 4; q++) {
      s8_t vz = zr[q];
      #pragma unroll
      for (int jj = 0; jj < 8; jj++) hrow[q * 8 + jj] += b2f(vz[jj]);
    }
  }
  #pragma unroll
  for (int d2 = 0; d2 < 32; d2++) s.u1.z2[t * 40 + d2] = f2b(hrow[d2]);
  __syncthreads();

  {
    int c = t & 31, gq = t >> 5;
    float s1 = 0.f, s2 = 0.f;
    for (int j = 0; j < 32; j++) {
      float vz = b2f((short)s.u1.z2[(gq * 32 + j) * 40 + c]);
      s1 += vz; s2 += vz * vz;
    }
    s.u2.redf[t] = s1; s.u2.redf[256 + t] = s2;
  }
  __syncthreads();
  if (t < 32) {
    float s1 = 0.f, s2 = 0.f;
    #pragma unroll
    for (int q = 0; q < 8; q++) { s1 += s.u2.redf[q * 32 + t]; s2 += s.u2.redf[256 + q * 32 + t]; }
    float mu = s1 * (1.f / 256.f);
    float var = s2 * (1.f / 256.f) - mu * mu;
    float a = g2[p * 32 + t] * rsqrtf(var + 1e-5f);
    s.u4.b.scA[t] = a; s.u4.b.shA[t] = be2[p * 32 + t] - a * mu;
  }
  __syncthreads();
  {
    int c = t & 31, gq = t >> 5;
    float a = s.u4.b.scA[c], bb = s.u4.b.shA[c];
    float s1 = 0.f;
    for (int j = 0; j < 32; j++) {
      int ad = (gq * 32 + j) * 40 + c;
      float vz = b2f((short)s.u1.z2[ad]);
      float hv = fmaxf(a * vz + bb, 0.f);
      s.u1.z2[ad] = f2b(hv);
      s1 += hv;
    }
    s.u2.redf[t] = s1;
  }
  __syncthreads();
  if (t < 32) {
    float s1 = 0.f;
    #pragma unroll
    for (int q = 0; q < 8; q++) s1 += s.u2.redf[q * 32 + t];
    rep_out[g * 32 + t] = s1 * (1.f / 256.f);
  }
  __syncthreads();

  {
    s8_t afr2[4];
    #pragma unroll
    for (int i = 0; i < 4; i++)
      afr2[i] = *(const s8_t*)&s.u1.z2[((wv * 4 + i) * 16 + l15) * 40 + quad * 8];
    float rAcc[4][4];
    #pragma unroll
    for (int i = 0; i < 4; i++)
      #pragma unroll
      for (int r = 0; r < 4; r++) rAcc[i][r] = 0.f;

    for (int half = 0; half < 2; half++) {
      __syncthreads();
      s.u2.redf[t] = 0.f; s.u2.redf[256 + t] = 0.f;
      __syncthreads();
      f4_t acc2[4][4];
      #pragma unroll
      for (int i = 0; i < 4; i++)
        #pragma unroll
        for (int nt = 0; nt < 4; nt++) acc2[i][nt] = (f4_t){0.f, 0.f, 0.f, 0.f};
      s8_t bfr[4];
      #pragma unroll
      for (int nt = 0; nt < 4; nt++) {
        const s4_t* pr = (const s4_t*)&s.dW1T[(half * 64 + nt * 16 + l15) * 36 + quad * 8];
        s4_t lo = pr[0], hi = pr[1];
        bfr[nt] = __builtin_shufflevector(lo, hi, 0, 1, 2, 3, 4, 5, 6, 7);
      }
      #pragma unroll
      for (int i = 0; i < 4; i++)
        #pragma unroll
        for (int nt = 0; nt < 4; nt++)
          acc2[i][nt] = __builtin_amdgcn_mfma_f32_16x16x32_bf16(afr2[i], bfr[nt], acc2[i][nt], 0, 0, 0);
      #pragma unroll
      for (int nt = 0; nt < 4; nt++) {
        float s1 = 0.f, s2 = 0.f;
        #pragma unroll
        for (int i = 0; i < 4; i++)
          #pragma unroll
          for (int r = 0; r < 4; r++) { float vv = acc2[i][nt][r]; s1 += vv; s2 += vv * vv; }
        atomicAdd(&s.u2.redf[nt * 16 + l15], s1);
        atomicAdd(&s.u2.redf[256 + nt * 16 + l15], s2);
      }
      __syncthreads();
      if (t < 64) {
        int col = half * 64 + t;
        float mu = s.u2.redf[t] * (1.f / 256.f);
        float var = s.u2.redf[256 + t] * (1.f / 256.f) - mu * mu;
        float a = dg[p * 128 + col] * rsqrtf(var + 1e-5f);
        s.u4.b.dscA[t] = a; s.u4.b.dshA[t] = dbe[p * 128 + col] - a * mu;
      }
      __syncthreads();
      #pragma unroll
      for (int nt = 0; nt < 4; nt++) {
        int cl = nt * 16 + l15;
        float a = s.u4.b.dscA[cl], bb = s.u4.b.dshA[cl], w2 = s.u3.b.dW2v[half * 64 + cl];
        #pragma unroll
        for (int i = 0; i < 4; i++)
          #pragma unroll
          for (int r = 0; r < 4; r++) {
            float dv = fmaxf(a * acc2[i][nt][r] + bb, 0.f);
            rAcc[i][r] += dv * w2;
          }
      }
    }
    #pragma unroll
    for (int off = 1; off < 16; off <<= 1)
      #pragma unroll
      for (int i = 0; i < 4; i++)
        #pragma unroll
        for (int r = 0; r < 4; r++) rAcc[i][r] += __shfl_xor(rAcc[i][r], off, 64);
    if (l15 == 0) {
      float sq = 0.f;
      #pragma unroll
      for (int i = 0; i < 4; i++)
        #pragma unroll
        for (int r = 0; r < 4; r++) {
          int m = (wv * 4 + i) * 16 + quad * 4 + r;
          float diff = rAcc[i][r] + db2v - s.f[m];
          sq += diff * diff;
        }
      atomicAdd(&s.rlacc, sq);
    }
  }
  __syncthreads();
  if (t == 0) rlp_out[g] = s.rlacc;
}

// ---------------------------------------------------------------------------
// ft matmul + Abar build + gcW bf16 pre-conversion. Grid = 12 blocks:
//   blocks 0-7:  z = concat(orig, rep) @ ftW (16 rows x 128 cols each)
//   block  8:    masked-GC Abar matrix
//   blocks 9-11: gcW layer (b-9) fp32 -> bf16 copy (same linear layout) so
//                k_patient stages half the bytes with no f2b VALU.
// All extra blocks run concurrently with the matmul blocks on idle CUs.
// ---------------------------------------------------------------------------
__global__ __launch_bounds__(256) void ft_mm(
    const float* __restrict__ orig, const float* __restrict__ rep,
    const float* __restrict__ ftW, float* __restrict__ hpre,
    const int* __restrict__ ps, const int* __restrict__ pd,
    const int* __restrict__ mask, unsigned short* __restrict__ abar,
    const float* __restrict__ gcW, unsigned short* __restrict__ gws)
{
  const int t = threadIdx.x;

  if (blockIdx.x >= 9) {
    const int layer = blockIdx.x - 9;
    const float* src = gcW + layer * 16384;
    unsigned short* dst = gws + layer * 16384;
    for (int idx = t; idx < 16384; idx += 256) dst[idx] = f2b(src[idx]);
    return;
  }

  if (blockIdx.x == 8) {
    __shared__ int aB[128 * 128];
    __shared__ int co[128], ci[128];
    __shared__ float facs[128], facd[128];
    for (int idx = t; idx < 16384; idx += 256) aB[idx] = 0;
    if (t < 128) { co[t] = 0; ci[t] = 0; }
    __syncthreads();
    for (int e = t; e < EPG_; e += 256) {
      int sN = ps[e], d = pd[e];
      atomicAdd(&co[sN], 1);
      atomicAdd(&ci[d], 1);
      atomicAdd(&aB[d * 128 + sN], 1);
    }
    __syncthreads();
    if (t < 128) {
      float mk = (float)mask[t];
      int da = co[t] > 1 ? co[t] : 1;
      int db = ci[t] > 1 ? ci[t] : 1;
      facs[t] = mk * rsqrtf((float)da);
      facd[t] = mk * rsqrtf((float)db);
    }
    __syncthreads();
    for (int idx = t; idx < 16384; idx += 256) {
      int d = idx >> 7, sN = idx & 127;
      abar[idx] = f2b((float)aB[idx] * facd[d] * facs[sN]);
    }
    return;
  }

  const int wv = t >> 6, lane = t & 63;
  const int l15 = lane & 15, quad = lane >> 4;
  const int m = blockIdx.x * 16 + l15;

  f4_t acc[2];
  acc[0] = (f4_t){0.f, 0.f, 0.f, 0.f};
  acc[1] = (f4_t){0.f, 0.f, 0.f, 0.f};
  for (int kt = 0; kt < 24; kt++) {
    int k0 = kt * 32 + quad * 8;
    const float* px = (k0 < 256) ? (orig + m * 256 + k0) : (rep + m * 512 + (k0 - 256));
    float4 xa = ((const float4*)px)[0];
    float4 xb = ((const float4*)px)[1];
    union { s8_t v; unsigned short u[8]; } fu;
    fu.u[0] = f2b(xa.x); fu.u[1] = f2b(xa.y); fu.u[2] = f2b(xa.z); fu.u[3] = f2b(xa.w);
    fu.u[4] = f2b(xb.x); fu.u[5] = f2b(xb.y); fu.u[6] = f2b(xb.z); fu.u[7] = f2b(xb.w);
    #pragma unroll
    for (int nt = 0; nt < 2; nt++) {
      int col = wv * 32 + nt * 16 + l15;
      union { s8_t v; unsigned short u[8]; } bu;
      #pragma unroll
      for (int j = 0; j < 8; j++) bu.u[j] = f2b(ftW[(k0 + j) * 128 + col]);
      acc[nt] = __builtin_amdgcn_mfma_f32_16x16x32_bf16(fu.v, bu.v, acc[nt], 0, 0, 0);
    }
  }
  #pragma unroll
  for (int nt = 0; nt < 2; nt++) {
    int col = wv * 32 + nt * 16 + l15;
    #pragma unroll
    for (int r = 0; r < 4; r++)
      hpre[(blockIdx.x * 16 + quad * 4 + r) * 128 + col] = acc[nt][r];
  }
}

// ---------------------------------------------------------------------------
// Fused patient stage: ONE block, 1024 threads (16 waves).
// gcW staging reads the pre-converted bf16 copy (half bytes, no f2b).
// ---------------------------------------------------------------------------
struct SmemB {
  __align__(16) unsigned short arow[128 * 136];  // Abar bf16, rows=dst
  __align__(16) unsigned short hT[128 * 136];    // h^T bf16 [feature][patient]
  union {
    struct {
      union {
        __align__(16) unsigned short wT[128 * 136]; // B^T staging (gcW/c1W)
        float zF[128 * 68];                         // cls pre-LN
      } w;
      __align__(16) unsigned short aggB[128 * 136]; // agg / hsum A-operand
    } mm;
  } u;
  float redA[1024], redB[1024];
  float scB[128], shB[128];
};

__global__ __launch_bounds__(1024) void k_patient(
    const float* __restrict__ hpre, const unsigned short* __restrict__ abar,
    const float* __restrict__ ftg, const float* __restrict__ ftbe,
    const unsigned short* __restrict__ gws, const float* __restrict__ gbng,
    const float* __restrict__ gbnbe,
    const float* __restrict__ c1W, const float* __restrict__ c1b,
    const float* __restrict__ lng, const float* __restrict__ lnbe,
    const float* __restrict__ c2W, const float* __restrict__ c2b,
    const float* __restrict__ rlp, float* __restrict__ out)
{
  __shared__ SmemB s;
  const int t = threadIdx.x;
  const int w = t >> 6, lane = t & 63;
  const int l15 = lane & 15, quad = lane >> 4;
  const int mb = w & 7, nb = (w >> 3) * 64;

  for (int idx = t; idx < 16384; idx += 1024) {
    int d = idx >> 7, sN = idx & 127;
    s.arow[d * 136 + sN] = abar[idx];
  }

  f4_t acc[4];
  #pragma unroll
  for (int nt = 0; nt < 4; nt++) {
    int col = nb + nt * 16 + l15;
    #pragma unroll
    for (int r = 0; r < 4; r++)
      acc[nt][r] = hpre[(mb * 16 + quad * 4 + r) * 128 + col];
  }

  float hR[16], hsumR[16];
  {
    #pragma unroll
    for (int nt = 0; nt < 4; nt++) {
      float s1 = acc[nt][0] + acc[nt][1] + acc[nt][2] + acc[nt][3];
      float s2 = acc[nt][0]*acc[nt][0] + acc[nt][1]*acc[nt][1] + acc[nt][2]*acc[nt][2] + acc[nt][3]*acc[nt][3];
      s1 += __shfl_xor(s1, 16, 64); s1 += __shfl_xor(s1, 32, 64);
      s2 += __shfl_xor(s2, 16, 64); s2 += __shfl_xor(s2, 32, 64);
      if (quad == 0) {
        s.redA[mb * 128 + nb + nt * 16 + l15] = s1;
        s.redB[mb * 128 + nb + nt * 16 + l15] = s2;
      }
    }
    __syncthreads();
    if (t < 128) {
      float a1 = 0.f, a2 = 0.f;
      #pragma unroll
      for (int q = 0; q < 8; q++) { a1 += s.redA[q * 128 + t]; a2 += s.redB[q * 128 + t]; }
      float mu = a1 * (1.f / 128.f), var = a2 * (1.f / 128.f) - mu * mu;
      float a = ftg[t] * rsqrtf(var + 1e-5f);
      s.scB[t] = a; s.shB[t] = ftbe[t] - a * mu;
    }
    __syncthreads();
    #pragma unroll
    for (int nt = 0; nt < 4; nt++) {
      int col = nb + nt * 16 + l15;
      float a = s.scB[col], bb = s.shB[col];
      #pragma unroll
      for (int r = 0; r < 4; r++) {
        int row = mb * 16 + quad * 4 + r;
        float hv = fmaxf(a * acc[nt][r] + bb, 0.f);
        hR[nt * 4 + r] = hv; hsumR[nt * 4 + r] = hv;
        s.hT[col * 136 + row] = f2b(hv);
      }
    }
  }
  __syncthreads();

  for (int layer = 0; layer < 3; layer++) {
    // stage gcW^T (pre-converted bf16) + agg = Abar @ h
    #pragma unroll
    for (int q = 0; q < 16; q++) {
      int idx = t + 1024 * q;
      int kk = idx >> 7, n = idx & 127;
      s.u.mm.w.wT[n * 136 + kk] = gws[layer * 16384 + idx];
    }
    f4_t ag[4];
    #pragma unroll
    for (int nt = 0; nt < 4; nt++) ag[nt] = (f4_t){0.f, 0.f, 0.f, 0.f};
    #pragma unroll
    for (int ks = 0; ks < 4; ks++) {
      s8_t afr = *(const s8_t*)&s.arow[(mb * 16 + l15) * 136 + ks * 32 + quad * 8];
      #pragma unroll
      for (int nt = 0; nt < 4; nt++) {
        s8_t bfr = *(const s8_t*)&s.hT[(nb + nt * 16 + l15) * 136 + ks * 32 + quad * 8];
        ag[nt] = __builtin_amdgcn_mfma_f32_16x16x32_bf16(afr, bfr, ag[nt], 0, 0, 0);
      }
    }
    #pragma unroll
    for (int nt = 0; nt < 4; nt++) {
      int col = nb + nt * 16 + l15;
      #pragma unroll
      for (int r = 0; r < 4; r++)
        s.u.mm.aggB[(mb * 16 + quad * 4 + r) * 136 + col] = f2b(ag[nt][r]);
    }
    __syncthreads();
    f4_t oc[4];
    #pragma unroll
    for (int nt = 0; nt < 4; nt++) oc[nt] = (f4_t){0.f, 0.f, 0.f, 0.f};
    #pragma unroll
    for (int ks = 0; ks < 4; ks++) {
      s8_t afr = *(const s8_t*)&s.u.mm.aggB[(mb * 16 + l15) * 136 + ks * 32 + quad * 8];
      #pragma unroll
      for (int nt = 0; nt < 4; nt++) {
        s8_t bfr = *(const s8_t*)&s.u.mm.w.wT[(nb + nt * 16 + l15) * 136 + ks * 32 + quad * 8];
        oc[nt] = __builtin_amdgcn_mfma_f32_16x16x32_bf16(afr, bfr, oc[nt], 0, 0, 0);
      }
    }
    #pragma unroll
    for (int nt = 0; nt < 4; nt++) {
      float s1 = oc[nt][0] + oc[nt][1] + oc[nt][2] + oc[nt][3];
      float s2 = oc[nt][0]*oc[nt][0] + oc[nt][1]*oc[nt][1] + oc[nt][2]*oc[nt][2] + oc[nt][3]*oc[nt][3];
      s1 += __shfl_xor(s1, 16, 64); s1 += __shfl_xor(s1, 32, 64);
      s2 += __shfl_xor(s2, 16, 64); s2 += __shfl_xor(s2, 32, 64);
      if (quad == 0) {
        s.redA[mb * 128 + nb + nt * 16 + l15] = s1;
        s.redB[mb * 128 + nb + nt * 16 + l15] = s2;
      }
    }
    __syncthreads();
    if (t < 128) {
      float a1 = 0.f, a2 = 0.f;
      #pragma unroll
      for (int q = 0; q < 8; q++) { a1 += s.redA[q * 128 + t]; a2 += s.redB[q * 128 + t]; }
      float mu = a1 * (1.f / 128.f), var = a2 * (1.f / 128.f) - mu * mu;
      float a = gbng[layer * 128 + t] * rsqrtf(var + 1e-5f);
      s.scB[t] = a; s.shB[t] = gbnbe[layer * 128 + t] - a * mu;
    }
    __syncthreads();
    #pragma unroll
    for (int nt = 0; nt < 4; nt++) {
      int col = nb + nt * 16 + l15;
      float a = s.scB[col], bb = s.shB[col];
      #pragma unroll
      for (int r = 0; r < 4; r++) {
        int row = mb * 16 + quad * 4 + r;
        float hn = fmaxf(a * oc[nt][r] + bb, 0.f) + hR[nt * 4 + r];
        hR[nt * 4 + r] = hn;
        hsumR[nt * 4 + r] += hn;
        s.hT[col * 136 + row] = f2b(hn);
      }
    }
    __syncthreads();
  }

  #pragma unroll
  for (int nt = 0; nt < 4; nt++) {
    int col = nb + nt * 16 + l15;
    #pragma unroll
    for (int r = 0; r < 4; r++)
      s.u.mm.aggB[(mb * 16 + quad * 4 + r) * 136 + col] = f2b(hsumR[nt * 4 + r] * 0.25f);
  }
  #pragma unroll
  for (int q = 0; q < 8; q++) {
    int idx = t + 1024 * q;
    int n = idx & 63, kk = idx >> 6;
    s.u.mm.w.wT[n * 136 + kk] = f2b(c1W[kk * 64 + n]);
  }
  __syncthreads();
  {
    const int nb2 = (w >> 3) * 32;
    f4_t zc[2];
    #pragma unroll
    for (int nt = 0; nt < 2; nt++) zc[nt] = (f4_t){0.f, 0.f, 0.f, 0.f};
    #pragma unroll
    for (int ks = 0; ks < 4; ks++) {
      s8_t afr = *(const s8_t*)&s.u.mm.aggB[(mb * 16 + l15) * 136 + ks * 32 + quad * 8];
      #pragma unroll
      for (int nt = 0; nt < 2; nt++) {
        s8_t bfr = *(const s8_t*)&s.u.mm.w.wT[(nb2 + nt * 16 + l15) * 136 + ks * 32 + quad * 8];
        zc[nt] = __builtin_amdgcn_mfma_f32_16x16x32_bf16(afr, bfr, zc[nt], 0, 0, 0);
      }
    }
    __syncthreads();   // wT reads done before zF (same bytes) writes
    #pragma unroll
    for (int nt = 0; nt < 2; nt++) {
      int col = nb2 + nt * 16 + l15;
      #pragma unroll
      for (int r = 0; r < 4; r++)
        s.u.mm.w.zF[(mb * 16 + quad * 4 + r) * 68 + col] = zc[nt][r] + c1b[col];
    }
  }
  __syncthreads();
  if (t < 128) {
    float s1 = 0.f, s2 = 0.f;
    #pragma unroll
    for (int j = 0; j < 64; j++) { float zv = s.u.mm.w.zF[t * 68 + j]; s1 += zv; s2 += zv * zv; }
    float mu = s1 * (1.f / 64.f);
    float var = s2 * (1.f / 64.f) - mu * mu;
    float rs = rsqrtf(var + 1e-5f);
    float l0 = 0.f, l1 = 0.f;
    #pragma unroll
    for (int j = 0; j < 64; j++) {
      float zv = s.u.mm.w.zF[t * 68 + j];
      float zn = fmaxf(lng[j] * (zv - mu) * rs + lnbe[j], 0.f);
      l0 += zn * c2W[j * 2];
      l1 += zn * c2W[j * 2 + 1];
    }
    out[t * 2]     = l0 + c2b[0];
    out[t * 2 + 1] = l1 + c2b[1];
  }

  {
    float r = rlp[t] + rlp[t + 1024];
    #pragma unroll
    for (int off = 32; off > 0; off >>= 1) r += __shfl_down(r, off, 64);
    if (lane == 0) s.redA[w] = r;
  }
  __syncthreads();
  if (t == 0) {
    float tot = 0.f;
    #pragma unroll
    for (int i = 0; i < 16; i++) tot += s.redA[i];
    out[256] = tot * (1.f / (256.f * 2048.f));
  }
}

// ---------------------------------------------------------------------------
extern "C" void kernel_launch(void* const* d_in, const int* in_sizes, int n_in,
                              void* d_out, int out_size, void* d_ws, size_t ws_size,
                              hipStream_t stream) {
  (void)in_sizes; (void)n_in; (void)out_size; (void)ws_size;
  const float* plane_feat  = (const float*)d_in[0];
  const int*   plane_src   = (const int*)d_in[1];
  const int*   plane_dst   = (const int*)d_in[2];
  const int*   patient_src = (const int*)d_in[3];
  const int*   patient_dst = (const int*)d_in[4];
  const float* orig        = (const float*)d_in[5];
  const int*   mask        = (const int*)d_in[6];
  const float* W1   = (const float*)d_in[7];
  const float* al1  = (const float*)d_in[8];
  const float* ar1  = (const float*)d_in[9];
  const float* res1 = (const float*)d_in[10];
  const float* b1   = (const float*)d_in[11];
  const float* g1   = (const float*)d_in[12];
  const float* be1  = (const float*)d_in[13];
  const float* W2   = (const float*)d_in[14];
  const float* al2  = (const float*)d_in[15];
  const float* ar2  = (const float*)d_in[16];
  const float* res2 = (const float*)d_in[17];
  const float* g2   = (const float*)d_in[19];
  const float* be2  = (const float*)d_in[20];
  const float* dW1  = (const float*)d_in[21];
  const float* dg   = (const float*)d_in[23];
  const float* dbe  = (const float*)d_in[24];
  const float* dW2  = (const float*)d_in[25];
  const float* db2  = (const float*)d_in[26];
  const float* ftW  = (const float*)d_in[27];
  const float* ftg  = (const float*)d_in[29];
  const float* ftbe = (const float*)d_in[30];
  const float* gcW  = (const float*)d_in[31];
  const float* gbng = (const float*)d_in[33];
  const float* gbnbe= (const float*)d_in[34];
  const float* c1W  = (const float*)d_in[35];
  const float* c1b  = (const float*)d_in[36];
  const float* lng  = (const float*)d_in[37];
  const float* lnbe = (const float*)d_in[38];
  const float* c2W  = (const float*)d_in[39];
  const float* c2b  = (const float*)d_in[40];

  float* ws   = (float*)d_ws;
  float* rep  = ws;                                     // [2048][32] = 65536 floats
  float* hpre = ws + 65536;                             // [128][128] ft matmul out
  unsigned short* abar = (unsigned short*)(ws + 81920); // [128][128] bf16 Abar
  float* rlp  = ws + 90112;                             // [2048] per-block rloss
  unsigned short* gws = (unsigned short*)(ws + 94208);  // [3][128][128] bf16 gcW
  float* outp = (float*)d_out;

  plane_enc<<<2048, 256, 0, stream>>>(plane_feat, plane_src, plane_dst,
      W1, al1, ar1, res1, b1, g1, be1, W2, al2, ar2, res2, g2, be2,
      dW1, dg, dbe, dW2, db2, rep, rlp);
  ft_mm<<<12, 256, 0, stream>>>(orig, rep, ftW, hpre,
      patient_src, patient_dst, mask, abar, gcW, gws);
  k_patient<<<1, 1024, 0, stream>>>(hpre, abar, ftg, ftbe,
      gws, gbng, gbnbe, c1W, c1b, lng, lnbe, c2W, c2b, rlp, outp);
}